// Round 3
// baseline (4493.335 us; speedup 1.0000x reference)
//
#include <hip/hip_runtime.h>
#include <hip/hip_bf16.h>

// ---------------------------------------------------------------------------
// LSTM (B=128, T=512, I=H=1024) + final FC (O=256) on gfx950.
// prep -> xcast -> gemm_xg (bf16, time-major, gate-interleaved cols) ->
// lstm_rec v6 -> fc_out.
//
// lstm_rec v6 = v5 + bounded-spin watchdog: the inter-block tag-poll gives
// up after 1024 retries and marks the block dead (fast fall-through). On a
// healthy run this is behavior-identical (polls resolve in <10 retries);
// on a co-residency/replay deadlock it converts "GPU hang -> container
// death" into "terminating run with wrong output" -- diagnosable.
//
// lstm_rec core (v4): 128 persistent blocks = 4 m-quarters x 32 n-blocks.
// Block = 32 batch rows x 32 h-cols; wave = 8 h-cols (N-split), K=1024 whole.
// w_hh slice lives ENTIRELY in VGPRs (256/lane, 1 wave/SIMD). h exchanged as
// self-validating tagged granules {h0,h1,tag=t} stored with ONE relaxed
// agent 8B atomic store -- no per-step fences, no flag array. Consumers
// poll-load the granules they need; tag mismatch -> retry. One __syncthreads
// per step. Gate layout per wave: permuted row
// n = ns*128 + w*32 + g*8 + jl  <->  orig g*1024 + (ns*32 + w*8 + jl).
// ---------------------------------------------------------------------------

typedef float  v4f  __attribute__((ext_vector_type(4)));
typedef __bf16 v8bf __attribute__((ext_vector_type(8)));
typedef __bf16 v4bf __attribute__((ext_vector_type(4)));

#define NBLK_REC 128

// ---------------- workspace layout (bytes) ----------------
static constexpr size_t XG_B    = (size_t)512 * 128 * 4096 * 2;      // 512 MiB
static constexpr size_t WIHP_O  = XG_B;
static constexpr size_t WHHP_O  = WIHP_O + (size_t)4096 * 1024 * 2;
static constexpr size_t BIASP_O = WHHP_O + (size_t)4096 * 1024 * 2;
static constexpr size_t HBUF_O  = BIASP_O + 16384;                   // 2*512KiB u64 granules
static constexpr size_t XB_O    = HBUF_O + (size_t)2 * 128 * 512 * 8;
static constexpr size_t WS_FULL = XB_O + (size_t)128 * 512 * 1024 * 2;

__device__ __forceinline__ float bf2f(unsigned short u) {
    union { unsigned u32; float f; } c; c.u32 = (unsigned)u << 16; return c.f;
}

// ---------------------------------------------------------------------------
// prep: permute+convert weights, tagged h0 granules, scrub parity-1 tags
// permutation: n = ns*128 + w*32 + g*8 + jl ; hcol = ns*32 + w*8 + jl
//              orig row = g*1024 + hcol
// ---------------------------------------------------------------------------
__global__ __launch_bounds__(256) void prep_kernel(
    const float* __restrict__ w_ih, const float* __restrict__ w_hh,
    const float* __restrict__ bias, const float* __restrict__ h0,
    __bf16* __restrict__ w_ihp, __bf16* __restrict__ w_hhp,
    float* __restrict__ biasp, unsigned long long* __restrict__ hb,
    int* __restrict__ unused)
{
    const int idx = blockIdx.x * 256 + threadIdx.x;       // 0 .. 4194303
    const int n = idx >> 10, k = idx & 1023;
    const int hcol = (n >> 7) * 32 + ((n >> 5) & 3) * 8 + (n & 7);
    const int g = (n >> 3) & 3;
    const int on = g * 1024 + hcol;
    w_ihp[idx] = (__bf16)w_ih[(size_t)on * 1024 + k];
    w_hhp[idx] = (__bf16)w_hh[(size_t)on * 1024 + k];
    if (idx < 4096) {
        const int hc2 = (idx >> 7) * 32 + ((idx >> 5) & 3) * 8 + (idx & 7);
        biasp[idx] = bias[((idx >> 3) & 3) * 1024 + hc2];
    }
    if (idx < 128 * 512) {   // tagged h0 granules, tag=0 (parity-0 buffer)
        const int m = idx >> 9, jp = idx & 511;
        union { __bf16 b; unsigned short u; } c0h, c1h;
        c0h.b = (__bf16)h0[(size_t)m * 1024 + jp * 2];
        c1h.b = (__bf16)h0[(size_t)m * 1024 + jp * 2 + 1];
        hb[idx] = (unsigned long long)c0h.u | ((unsigned long long)c1h.u << 16);
        hb[65536 + idx] = 0xFFFFull << 32;   // parity-1: never-matching tag
    }
    (void)unused;
}

// ---------------------------------------------------------------------------
__global__ __launch_bounds__(256) void xcast(
    const float* __restrict__ x, __bf16* __restrict__ xb)
{
    const size_t i = ((size_t)blockIdx.x * 256 + threadIdx.x) * 8;
    const float4 a = *(const float4*)&x[i];
    const float4 b = *(const float4*)&x[i + 4];
    v8bf o = { (__bf16)a.x, (__bf16)a.y, (__bf16)a.z, (__bf16)a.w,
               (__bf16)b.x, (__bf16)b.y, (__bf16)b.z, (__bf16)b.w };
    *(v8bf*)&xb[i] = o;
}

// ---------------------------------------------------------------------------
// gemm_xg (bf16): xg[t][b][hcol][g] = bf16( xb . w_ihp + biasp ), gate-
// interleaved columns. Tile 128x128, 4 waves 2x2, BK=64, LDS epilogue.
// col remap inside tile: nl(permuted) -> outl = (w*8+jl)*4 + g.
// ---------------------------------------------------------------------------
__global__ __launch_bounds__(256) void gemm_xg_bf16(
    const __bf16* __restrict__ xb, const __bf16* __restrict__ wih,
    const float* __restrict__ biasp, __bf16* __restrict__ xg)
{
    const int bx = blockIdx.x;
    const int mtile = bx >> 5, ntile = bx & 31;
    const int m0 = mtile << 7, n0 = ntile << 7;
    const int bb = mtile >> 2, t0 = (mtile & 3) << 7;
    const int tid = threadIdx.x;
    const int lane = tid & 63, wave = tid >> 6;
    const int wm = wave >> 1, wn = wave & 1;
    const int l15 = lane & 15, q = lane >> 4;

    __shared__ union {
        struct { __bf16 A[128][72]; __bf16 B[128][72]; } s;
        __bf16 C[128][132];
    } u;

    const int sr = tid >> 3, sc = (tid & 7) * 8;
    const __bf16* ag = xb  + (size_t)(m0 + sr) * 1024 + sc;
    const __bf16* bg = wih + (size_t)(n0 + sr) * 1024 + sc;

    v4f acc[4][4] = {};
    for (int kt = 0; kt < 16; ++kt) {
        __syncthreads();
        #pragma unroll
        for (int i = 0; i < 4; ++i) {
            *(v8bf*)&u.s.A[sr + i * 32][sc] = *(const v8bf*)(ag + (size_t)i * 32 * 1024 + kt * 64);
            *(v8bf*)&u.s.B[sr + i * 32][sc] = *(const v8bf*)(bg + (size_t)i * 32 * 1024 + kt * 64);
        }
        __syncthreads();
        v8bf a[2][4], b[2][4];
        #pragma unroll
        for (int ks = 0; ks < 2; ++ks) {
            #pragma unroll
            for (int im = 0; im < 4; ++im)
                a[ks][im] = *(const v8bf*)&u.s.A[wm * 64 + im * 16 + l15][ks * 32 + q * 8];
            #pragma unroll
            for (int in_ = 0; in_ < 4; ++in_)
                b[ks][in_] = *(const v8bf*)&u.s.B[wn * 64 + in_ * 16 + l15][ks * 32 + q * 8];
        }
        #pragma unroll
        for (int ks = 0; ks < 2; ++ks)
            #pragma unroll
            for (int im = 0; im < 4; ++im)
                #pragma unroll
                for (int in_ = 0; in_ < 4; ++in_)
                    acc[im][in_] = __builtin_amdgcn_mfma_f32_16x16x32_bf16(
                        a[ks][im], b[ks][in_], acc[im][in_], 0, 0, 0);
    }
    __syncthreads();
    #pragma unroll
    for (int in_ = 0; in_ < 4; ++in_) {
        const int nl = wn * 64 + in_ * 16 + l15;
        const int outl = (((nl >> 5) * 8 + (nl & 7)) << 2) | ((nl >> 3) & 3);
        const float bv = biasp[n0 + nl];
        #pragma unroll
        for (int im = 0; im < 4; ++im)
            #pragma unroll
            for (int r = 0; r < 4; ++r)
                u.C[wm * 64 + im * 16 + q * 4 + r][outl] = (__bf16)(acc[im][in_][r] + bv);
    }
    __syncthreads();
    const int cr = tid >> 1, chf = (tid & 1) * 64;
    __bf16* outp = xg + ((size_t)(t0 + cr) * 128 + bb) * 4096 + n0 + chf;
    #pragma unroll
    for (int j = 0; j < 8; ++j)
        *(uint4*)(outp + j * 8) = *(const uint4*)&u.C[cr][chf + j * 8];
}

// fallback: fp32 A staging (used only if ws too small for xb)
__global__ __launch_bounds__(256) void gemm_xg_f32(
    const float* __restrict__ x, const __bf16* __restrict__ wih,
    const float* __restrict__ biasp, __bf16* __restrict__ xg)
{
    const int bx = blockIdx.x;
    const int mtile = bx >> 5, ntile = bx & 31;
    const int m0 = mtile << 7, n0 = ntile << 7;
    const int bb = mtile >> 2, t0 = (mtile & 3) << 7;
    const int tid = threadIdx.x;
    const int lane = tid & 63, wave = tid >> 6;
    const int wm = wave >> 1, wn = wave & 1;
    const int l15 = lane & 15, q = lane >> 4;

    __shared__ __bf16 Al[128][40];
    __shared__ __bf16 Bl[128][40];
    v4f acc[4][4] = {};

    for (int kt = 0; kt < 32; ++kt) {
        __syncthreads();
        const int k0 = kt * 32;
        #pragma unroll
        for (int i = 0; i < 4; ++i) {
            const int s = tid + i * 256, r = s >> 3, c = s & 7;
            const float4 v = *(const float4*)&x[(size_t)(m0 + r) * 1024 + k0 + c * 4];
            v4bf pk = { (__bf16)v.x, (__bf16)v.y, (__bf16)v.z, (__bf16)v.w };
            *(v4bf*)&Al[r][c * 4] = pk;
        }
        #pragma unroll
        for (int j = 0; j < 2; ++j) {
            const int s = tid + j * 256, r = s >> 2, ch = s & 3;
            const uint4 v = *(const uint4*)&wih[(size_t)(n0 + r) * 1024 + k0 + ch * 8];
            *(uint4*)&Bl[r][ch * 8] = v;
        }
        __syncthreads();
        v8bf a[4], b[4];
        #pragma unroll
        for (int im = 0; im < 4; ++im) a[im] = *(const v8bf*)&Al[wm * 64 + im * 16 + l15][q * 8];
        #pragma unroll
        for (int in_ = 0; in_ < 4; ++in_) b[in_] = *(const v8bf*)&Bl[wn * 64 + in_ * 16 + l15][q * 8];
        #pragma unroll
        for (int im = 0; im < 4; ++im)
            #pragma unroll
            for (int in_ = 0; in_ < 4; ++in_)
                acc[im][in_] = __builtin_amdgcn_mfma_f32_16x16x32_bf16(a[im], b[in_], acc[im][in_], 0, 0, 0);
    }
    #pragma unroll
    for (int in_ = 0; in_ < 4; ++in_) {
        const int nl = wn * 64 + in_ * 16 + l15;
        const int outl = (((nl >> 5) * 8 + (nl & 7)) << 2) | ((nl >> 3) & 3);
        const float bv = biasp[n0 + nl];
        #pragma unroll
        for (int im = 0; im < 4; ++im) {
            const int mbase = wm * 64 + im * 16 + q * 4;
            #pragma unroll
            for (int r = 0; r < 4; ++r)
                xg[((size_t)(t0 + mbase + r) * 128 + bb) * 4096 + n0 + outl] =
                    (__bf16)(acc[im][in_][r] + bv);
        }
    }
}

// ---------------------------------------------------------------------------
// lstm_rec v6 (= v5 + bounded-spin watchdog)
// ---------------------------------------------------------------------------
__device__ __forceinline__ float sigm_f(float x) {
    return __builtin_amdgcn_rcpf(1.f + __expf(-x));
}
__device__ __forceinline__ float tanh_f(float x) {
    return 1.f - 2.f * __builtin_amdgcn_rcpf(__expf(2.f * x) + 1.f);
}

__global__ __launch_bounds__(256, 1) void lstm_rec(
    const __bf16* __restrict__ whh, const __bf16* __restrict__ xg,
    const float* __restrict__ c0, const float* __restrict__ h0,
    unsigned long long* hbuf)
{
    const int tid  = threadIdx.x;
    const int lane = tid & 63, w = tid >> 6;
    const int l15  = lane & 15, q = lane >> 4;
    const int mq   = blockIdx.x >> 5;   // quarter (32 batch rows)
    const int ns   = blockIdx.x & 31;   // n-block (32 h-cols)

    __shared__ __bf16 hA[2][32][1032];  // staged h(t-1), padded pitch (132 KiB)

    // ---- replay-safe self-init of the granules this block OWNS ----
    // Parity-0 <- h0 (tag 0); parity-1 <- never-matching tag. Idempotent
    // under rocprof dispatch-replay (which re-runs lstm_rec WITHOUT prep).
    {
        unsigned long long* hb0 = hbuf;            // parity-0
        unsigned long long* hb1 = hbuf + 65536;    // parity-1
        #pragma unroll
        for (int k2 = 0; k2 < 2; ++k2) {
            const int s   = tid + k2 * 256;        // 0..511
            const int r   = s >> 4;                // row-in-block 0..31
            const int jpl = s & 15;                // u64 col-in-block 0..15
            const int m   = mq * 32 + r;
            const int jp  = ns * 16 + jpl;
            union { __bf16 b; unsigned short u; } a0, a1;
            a0.b = (__bf16)h0[(size_t)m * 1024 + jp * 2];
            a1.b = (__bf16)h0[(size_t)m * 1024 + jp * 2 + 1];
            const unsigned long long g0 = (unsigned long long)a0.u
                                        | ((unsigned long long)a1.u << 16);   // tag 0
            __hip_atomic_store(hb0 + (size_t)m * 512 + jp, g0,
                               __ATOMIC_RELAXED, __HIP_MEMORY_SCOPE_AGENT);
            __hip_atomic_store(hb1 + (size_t)m * 512 + jp, 0xFFFFull << 32,
                               __ATOMIC_RELAXED, __HIP_MEMORY_SCOPE_AGENT);
        }
        __threadfence();   // one-time: drain init stores before the loop
    }

    // ---- w_hh slice -> VGPRs (wave w: 32 gate rows x 1024 k = 256 VGPR) ----
    v8bf breg[2][32];
    {
        const __bf16* wb = whh + (size_t)(ns * 128 + w * 32) * 1024;
        #pragma unroll
        for (int ni = 0; ni < 2; ++ni)
            #pragma unroll
            for (int kc = 0; kc < 32; ++kc)
                breg[ni][kc] = *(const v8bf*)&wb[(size_t)(ni * 16 + l15) * 1024 + kc * 32 + q * 8];
    }

    // epilogue identity: lane handles (mi rows-half, h-col j)
    const int j    = l15 & 7;
    const int mi   = (l15 >> 3) & 1;
    const int hcol = ns * 32 + w * 8 + j;
    const int row0 = mi * 16 + q * 4;          // local rows row0..row0+3
    float c_[4];
    #pragma unroll
    for (int r = 0; r < 4; ++r)
        c_[r] = c0[(size_t)(mq * 32 + row0 + r) * 1024 + hcol];

    // watchdog state: once a poll exceeds the bound, stop polling entirely.
    // Healthy runs never trigger (polls resolve in <10 retries); a
    // co-residency deadlock terminates in ~ms with wrong output instead of
    // hanging the queue and killing the container.
    bool dead = false;

    #pragma unroll 1
    for (int t = 1; t <= 512; ++t) {
        const int par  = (t - 1) & 1;
        const unsigned short want = (unsigned short)(t - 1);

        // ---- xg prefetch (plain loads, gate-interleaved granules) ----
        unsigned long long xq[4];
        {
            const unsigned long long* xp = (const unsigned long long*)xg
                + ((size_t)(t - 1) * 128 + mq * 32 + row0) * 1024 + hcol;
            #pragma unroll
            for (int r = 0; r < 4; ++r) xq[r] = xp[(size_t)r * 1024];
        }

        // ---- phase 1: cooperative tagged load of h(t-1) -> LDS ----
        {
            const unsigned long long* hq = hbuf + (size_t)par * 65536;
            #pragma unroll 1
            for (int r2 = 0; r2 < 8; ++r2) {
                const int rowl = w * 8 + r2;
                const unsigned long long* base = hq + (size_t)(mq * 32 + rowl) * 512;
                unsigned long long gv[8];
                #pragma unroll
                for (int c = 0; c < 8; ++c)
                    gv[c] = __hip_atomic_load(base + c * 64 + lane,
                                              __ATOMIC_RELAXED, __HIP_MEMORY_SCOPE_AGENT);
                int spin = 0;
                for (;;) {
                    bool ok = true;
                    #pragma unroll
                    for (int c = 0; c < 8; ++c)
                        ok &= ((unsigned short)(gv[c] >> 32) == want);
                    if (ok | dead) break;
                    if (++spin > 1024) { dead = true; break; }   // watchdog
                    #pragma unroll
                    for (int c = 0; c < 8; ++c)
                        gv[c] = __hip_atomic_load(base + c * 64 + lane,
                                                  __ATOMIC_RELAXED, __HIP_MEMORY_SCOPE_AGENT);
                }
                #pragma unroll
                for (int c = 0; c < 8; ++c)
                    *(unsigned*)&hA[par][rowl][(c * 64 + lane) * 2] = (unsigned)gv[c];
            }
        }
        __syncthreads();   // the ONLY barrier per step

        // ---- phase 2: MFMA  (A from LDS, B from VGPRs) ----
        v4f acc[2][2] = {};
        #pragma unroll
        for (int kc = 0; kc < 32; ++kc) {
            const v8bf a0 = *(const v8bf*)&hA[par][l15][kc * 32 + q * 8];
            const v8bf a1 = *(const v8bf*)&hA[par][l15 + 16][kc * 32 + q * 8];
            acc[0][0] = __builtin_amdgcn_mfma_f32_16x16x32_bf16(a0, breg[0][kc], acc[0][0], 0, 0, 0);
            acc[0][1] = __builtin_amdgcn_mfma_f32_16x16x32_bf16(a0, breg[1][kc], acc[0][1], 0, 0, 0);
            acc[1][0] = __builtin_amdgcn_mfma_f32_16x16x32_bf16(a1, breg[0][kc], acc[1][0], 0, 0, 0);
            acc[1][1] = __builtin_amdgcn_mfma_f32_16x16x32_bf16(a1, breg[1][kc], acc[1][1], 0, 0, 0);
        }

        // ---- phase 3: gate assembly via shfl_xor(8), cell, tagged h store ----
        v4f s0 = mi ? acc[0][0] : acc[1][0];
        v4f s1 = mi ? acc[0][1] : acc[1][1];
        v4f r0, r1;
        #pragma unroll
        for (int r = 0; r < 4; ++r) {
            r0[r] = __shfl_xor(s0[r], 8);
            r1[r] = __shfl_xor(s1[r], 8);
        }
        const v4f own0 = mi ? acc[1][0] : acc[0][0];
        const v4f own1 = mi ? acc[1][1] : acc[0][1];

        unsigned hw[4];
        #pragma unroll
        for (int r = 0; r < 4; ++r) {
            const float iv = (mi ? r0[r]   : own0[r]) + bf2f((unsigned short)(xq[r]));
            const float fv = (mi ? own0[r] : r0[r])   + bf2f((unsigned short)(xq[r] >> 16));
            const float gv = (mi ? r1[r]   : own1[r]) + bf2f((unsigned short)(xq[r] >> 32));
            const float ov = (mi ? own1[r] : r1[r])   + bf2f((unsigned short)(xq[r] >> 48));
            c_[r] = sigm_f(fv) * c_[r] + sigm_f(iv) * tanh_f(gv);
            const float hv = sigm_f(ov) * tanh_f(c_[r]);
            union { __bf16 b; unsigned short u; } cv; cv.b = (__bf16)hv;
            hw[r] = cv.u;
        }
        // pair columns (j even keeps low, partner j+1 supplies high)
        unsigned long long* hd = hbuf + (size_t)(t & 1) * 65536
                               + (size_t)(mq * 32 + row0) * 512 + (hcol >> 1);
        #pragma unroll
        for (int r = 0; r < 4; ++r) {
            const unsigned ph = __shfl_xor(hw[r], 1);
            if ((j & 1) == 0) {
                const unsigned long long wrd = (unsigned long long)(hw[r] | (ph << 16))
                                             | ((unsigned long long)(unsigned short)t << 32);
                __hip_atomic_store(hd + (size_t)r * 512, wrd,
                                   __ATOMIC_RELAXED, __HIP_MEMORY_SCOPE_AGENT);
            }
        }
    }
}

// ---------------------------------------------------------------------------
// fc_out: out[b][o] = h_last[b] . w_fc[o] + b_fc[o]  (h_last: tagged granules,
// parity-0 buffer since t=512 is even)
// ---------------------------------------------------------------------------
__global__ __launch_bounds__(256) void fc_out(
    const unsigned long long* __restrict__ hb, const float* __restrict__ wfc,
    const float* __restrict__ bfc, float* __restrict__ out)
{
    const int b = blockIdx.x, o = threadIdx.x;
    __shared__ float hs[1024];
    for (int i = threadIdx.x; i < 512; i += 256) {
        const unsigned long long g = hb[(size_t)b * 512 + i];
        hs[2 * i]     = bf2f((unsigned short)g);
        hs[2 * i + 1] = bf2f((unsigned short)(g >> 16));
    }
    __syncthreads();
    const float* wr = wfc + (size_t)o * 1024;
    float s = 0.f;
    for (int k = 0; k < 1024; k += 4) {
        const float4 w = *(const float4*)&wr[k];
        s += hs[k] * w.x + hs[k + 1] * w.y + hs[k + 2] * w.z + hs[k + 3] * w.w;
    }
    out[b * 256 + o] = s + bfc[o];
}

// ---------------------------------------------------------------------------
extern "C" void kernel_launch(void* const* d_in, const int* in_sizes, int n_in,
                              void* d_out, int out_size, void* d_ws, size_t ws_size,
                              hipStream_t stream) {
    (void)in_sizes; (void)n_in; (void)out_size;
    const float* x    = (const float*)d_in[0];
    const float* h0   = (const float*)d_in[1];
    const float* c0   = (const float*)d_in[2];
    const float* w_ih = (const float*)d_in[3];
    const float* w_hh = (const float*)d_in[4];
    const float* bias = (const float*)d_in[5];
    const float* w_fc = (const float*)d_in[6];
    const float* b_fc = (const float*)d_in[7];
    float* out = (float*)d_out;

    char* ws = (char*)d_ws;
    __bf16* xg    = (__bf16*)(ws);
    __bf16* w_ihp = (__bf16*)(ws + WIHP_O);
    __bf16* w_hhp = (__bf16*)(ws + WHHP_O);
    float*  biasp = (float*)(ws + BIASP_O);
    unsigned long long* hbuf = (unsigned long long*)(ws + HBUF_O);
    __bf16* xb    = (__bf16*)(ws + XB_O);

    prep_kernel<<<16384, 256, 0, stream>>>(w_ih, w_hh, bias, h0, w_ihp, w_hhp, biasp, hbuf, nullptr);
    if (ws_size >= WS_FULL) {
        xcast<<<32768, 256, 0, stream>>>(x, xb);
        gemm_xg_bf16<<<16384, 256, 0, stream>>>(xb, w_ihp, biasp, xg);
    } else {
        gemm_xg_f32<<<16384, 256, 0, stream>>>(x, w_ihp, biasp, xg);
    }
    lstm_rec<<<NBLK_REC, 256, 0, stream>>>(w_hhp, xg, c0, h0, hbuf);
    fc_out<<<128, 256, 0, stream>>>(hbuf, w_fc, b_fc, out);
}